// Round 1
// baseline (244.603 us; speedup 1.0000x reference)
//
#include <hip/hip_runtime.h>
#include <math.h>

// B=65536, S=64.
// Outputs (concat, f32): L (B,S,3) at offset 0, basis_out (B,S,3,3) at B*S*3.
// Memory-bound: ~192 MB writes + ~50 MB reads -> ~38 us floor at 6.3 TB/s.

constexpr int S = 64;

__global__ __launch_bounds__(256) void cosine_lobe_kernel(
    const float* __restrict__ viewdir,
    const float* __restrict__ normal,
    const float* __restrict__ r1,
    const void*  __restrict__ ray_mask,   // int32 0/1 or u8 0/1 -- auto-detected
    const float* __restrict__ angs,
    float* __restrict__ out,
    int B)
{
    __shared__ float sL[256 * 3];   // staged L for coalesced writeout
    __shared__ float sM[256];       // mask as float per (b,s)
    __shared__ float sB[4 * 9];     // basis^T (flat, output order) per local b
    __shared__ int   s_u8;

    const int tid = threadIdx.x;
    const int gid = blockIdx.x * 256 + tid;
    const int b = gid >> 6;          // wave-uniform: one b per 64-lane wave
    const int s = gid & 63;

    // --- detect ray_mask element width (int32 vs byte-bool) ---
    if (tid == 0) {
        const unsigned int* w = (const unsigned int*)ray_mask;
        unsigned int acc = 0;
#pragma unroll
        for (int i = 0; i < 16; ++i) acc |= w[i];
        s_u8 = (acc > 1u) ? 1 : 0;   // byte-packed bools make some word >1
    }
    __syncthreads();
    const bool u8mode = (s_u8 != 0);

    // --- per-b frame (redundant across the wave; L1-broadcast loads) ---
    const float nx = normal[b * 3 + 0];
    const float ny = normal[b * 3 + 1];
    const float nz = normal[b * 3 + 2];

    float ux, uy, uz;
    if (nz < 0.9f) { ux = 0.0f; uy = 0.0f; uz = 1.0f; }
    else           { ux = -1.0f; uy = 0.0f; uz = 0.0f; }

    // tangent = normalize(cross(up, normal))
    float tx = uy * nz - uz * ny;
    float ty = uz * nx - ux * nz;
    float tz = ux * ny - uy * nx;
    float inv = 1.0f / (sqrtf(tx * tx + ty * ty + tz * tz) + 1e-8f);
    tx *= inv; ty *= inv; tz *= inv;

    // bitangent = normalize(cross(normal, tangent))
    float bx = ny * tz - nz * ty;
    float by = nz * tx - nx * tz;
    float bz = nx * ty - ny * tx;
    inv = 1.0f / (sqrtf(bx * bx + by * by + bz * bz) + 1e-8f);
    bx *= inv; by *= inv; bz *= inv;

    // --- per-(b,s) sample ---
    const float2 a = ((const float2*)angs)[gid];   // coalesced 8B/lane
    float st, ct, sp, cp;
    sincospif(a.x, &st, &ct);                      // theta = u1*pi
    sincospif(2.0f * a.y, &sp, &cp);               // phi   = 2*u2*pi
    const float r = r1[b];
    float hx = r * ct * cp;
    float hy = r * ct * sp;
    float hz = 1.0f - r * st;                      // r*(-sin) + e3.z
    inv = 1.0f / (sqrtf(hx * hx + hy * hy + hz * hz) + 1e-8f);
    hx *= inv; hy *= inv; hz *= inv;
    if (s == 0) { hx = 0.0f; hy = 0.0f; hz = 1.0f; }  // H_l[:,0,:] = e3

    // H = H_l . basis  (einsum bsj,bji->bsi)
    const float Hx = hx * tx + hy * bx + hz * nx;
    const float Hy = hx * ty + hy * by + hz * ny;
    const float Hz = hx * tz + hy * bz + hz * nz;

    const float vx = viewdir[b * 3 + 0];
    const float vy = viewdir[b * 3 + 1];
    const float vz = viewdir[b * 3 + 2];
    const float d2 = 2.0f * (vx * Hx + vy * Hy + vz * Hz);

    float m;
    if (u8mode) m = (float)((const unsigned char*)ray_mask)[gid];
    else        m = (float)((const int*)ray_mask)[gid];

    // --- stage L + mask + basis in LDS for coalesced writeout ---
    sL[tid * 3 + 0] = (d2 * Hx - vx) * m;
    sL[tid * 3 + 1] = (d2 * Hy - vy) * m;
    sL[tid * 3 + 2] = (d2 * Hz - vz) * m;
    sM[tid] = m;
    if (s == 0) {
        // basis_out flat order per s: [tx,bx,nx, ty,by,ny, tz,bz,nz]
        float* p = &sB[(tid >> 6) * 9];
        p[0] = tx; p[1] = bx; p[2] = nx;
        p[3] = ty; p[4] = by; p[5] = ny;
        p[6] = tz; p[7] = bz; p[8] = nz;
    }
    __syncthreads();

    // L: block region [blockIdx*768, +768) -- unit-stride stores
    float* Lout = out + (size_t)blockIdx.x * 768;
#pragma unroll
    for (int j = 0; j < 3; ++j) {
        const int f = j * 256 + tid;
        Lout[f] = sL[f];
    }

    // basis_out: block region [B*S*3 + blockIdx*2304, +2304) -- unit-stride
    float* Bout = out + (size_t)B * S * 3 + (size_t)blockIdx.x * 2304;
#pragma unroll
    for (int j = 0; j < 9; ++j) {
        const int f = j * 256 + tid;
        const int ls = f / 9;            // local (b,s) element 0..255
        const int k  = f - ls * 9;       // component 0..8
        Bout[f] = sB[(ls >> 6) * 9 + k] * sM[ls];
    }
}

extern "C" void kernel_launch(void* const* d_in, const int* in_sizes, int n_in,
                              void* d_out, int out_size, void* d_ws, size_t ws_size,
                              hipStream_t stream) {
    const float* viewdir = (const float*)d_in[0];
    const float* normal  = (const float*)d_in[1];
    const float* r1      = (const float*)d_in[2];
    // d_in[3] = r2 -- unused by the reference computation
    const void*  mask    = d_in[4];
    const float* angs    = (const float*)d_in[5];

    const int B = in_sizes[2];            // 65536
    const int nBlocks = (B * S) / 256;    // 16384

    cosine_lobe_kernel<<<nBlocks, 256, 0, stream>>>(
        viewdir, normal, r1, mask, angs, (float*)d_out, B);
}

// Round 2
// 244.575 us; speedup vs baseline: 1.0001x; 1.0001x over previous
//
#include <hip/hip_runtime.h>
#include <math.h>

// B=65536, S=64.
// Outputs (concat, f32): L (B,S,3) at offset 0, basis_out (B,S,3,3) at B*S*3.
// Memory-bound: ~201 MB writes + ~48 MB reads -> ~38 us floor at 6.6 TB/s.
//
// Writeout strategy: expand everything into LDS (odd strides 3 and 9 ->
// only 2-way bank aliasing, which is free on gfx950), then emit pure
// dwordx4 sweeps with no per-element index math.

constexpr int S = 64;

__global__ __launch_bounds__(256) void cosine_lobe_kernel(
    const float* __restrict__ viewdir,
    const float* __restrict__ normal,
    const float* __restrict__ r1,
    const void*  __restrict__ ray_mask,   // int32 0/1 or u8 0/1 -- auto-detected
    const float* __restrict__ angs,
    float* __restrict__ out,
    int B)
{
    __shared__ __align__(16) float sL[256 * 3];    // staged L
    __shared__ __align__(16) float sBas[256 * 9];  // staged masked basis_out
    __shared__ int s_u8;

    const int tid = threadIdx.x;
    const int gid = blockIdx.x * 256 + tid;
    const int b = gid >> 6;          // wave-uniform: one b per 64-lane wave
    const int s = gid & 63;

    // --- detect ray_mask element width (int32 vs byte-bool) ---
    if (tid == 0) {
        const unsigned int* w = (const unsigned int*)ray_mask;
        unsigned int acc = 0;
#pragma unroll
        for (int i = 0; i < 16; ++i) acc |= w[i];
        s_u8 = (acc > 1u) ? 1 : 0;   // byte-packed bools make some word >1
    }

    // --- per-b frame (redundant across the wave; L1-broadcast loads) ---
    const float nx = normal[b * 3 + 0];
    const float ny = normal[b * 3 + 1];
    const float nz = normal[b * 3 + 2];

    float ux, uy, uz;
    if (nz < 0.9f) { ux = 0.0f; uy = 0.0f; uz = 1.0f; }
    else           { ux = -1.0f; uy = 0.0f; uz = 0.0f; }

    // tangent = normalize(cross(up, normal))
    float tx = uy * nz - uz * ny;
    float ty = uz * nx - ux * nz;
    float tz = ux * ny - uy * nx;
    float inv = 1.0f / (sqrtf(tx * tx + ty * ty + tz * tz) + 1e-8f);
    tx *= inv; ty *= inv; tz *= inv;

    // bitangent = normalize(cross(normal, tangent))
    float bx = ny * tz - nz * ty;
    float by = nz * tx - nx * tz;
    float bz = nx * ty - ny * tx;
    inv = 1.0f / (sqrtf(bx * bx + by * by + bz * bz) + 1e-8f);
    bx *= inv; by *= inv; bz *= inv;

    // --- per-(b,s) sample ---
    const float2 a = ((const float2*)angs)[gid];   // coalesced 8B/lane
    float st, ct, sp, cp;
    sincospif(a.x, &st, &ct);                      // theta = u1*pi
    sincospif(2.0f * a.y, &sp, &cp);               // phi   = 2*u2*pi
    const float r = r1[b];
    float hx = r * ct * cp;
    float hy = r * ct * sp;
    float hz = 1.0f - r * st;                      // r*(-sin) + e3.z
    inv = 1.0f / (sqrtf(hx * hx + hy * hy + hz * hz) + 1e-8f);
    hx *= inv; hy *= inv; hz *= inv;
    if (s == 0) { hx = 0.0f; hy = 0.0f; hz = 1.0f; }  // H_l[:,0,:] = e3

    // H = H_l . basis  (einsum bsj,bji->bsi)
    const float Hx = hx * tx + hy * bx + hz * nx;
    const float Hy = hx * ty + hy * by + hz * ny;
    const float Hz = hx * tz + hy * bz + hz * nz;

    const float vx = viewdir[b * 3 + 0];
    const float vy = viewdir[b * 3 + 1];
    const float vz = viewdir[b * 3 + 2];
    const float d2 = 2.0f * (vx * Hx + vy * Hy + vz * Hz);

    __syncthreads();                 // covers s_u8 visibility
    float m;
    if (s_u8) m = (float)((const unsigned char*)ray_mask)[gid];
    else      m = (float)((const int*)ray_mask)[gid];

    // --- stage expanded outputs in LDS ---
    sL[tid * 3 + 0] = (d2 * Hx - vx) * m;          // stride 3: 2-way alias, free
    sL[tid * 3 + 1] = (d2 * Hy - vy) * m;
    sL[tid * 3 + 2] = (d2 * Hz - vz) * m;

    float* p = &sBas[tid * 9];                     // stride 9: 2-way alias, free
    p[0] = tx * m; p[1] = bx * m; p[2] = nx * m;   // basis_T row-major per s
    p[3] = ty * m; p[4] = by * m; p[5] = ny * m;
    p[6] = tz * m; p[7] = bz * m; p[8] = nz * m;
    __syncthreads();

    // --- pure dwordx4 writeout, no per-element index math ---
    const float4* sL4 = (const float4*)sL;     // 192 vec4
    const float4* sB4 = (const float4*)sBas;   // 576 vec4

    float4* Lout4 = (float4*)(out + (size_t)blockIdx.x * 768);
    if (tid < 192) Lout4[tid] = sL4[tid];

    float4* Bout4 = (float4*)(out + (size_t)B * S * 3 + (size_t)blockIdx.x * 2304);
    Bout4[tid]       = sB4[tid];
    Bout4[256 + tid] = sB4[256 + tid];
    if (tid < 64) Bout4[512 + tid] = sB4[512 + tid];
}

extern "C" void kernel_launch(void* const* d_in, const int* in_sizes, int n_in,
                              void* d_out, int out_size, void* d_ws, size_t ws_size,
                              hipStream_t stream) {
    const float* viewdir = (const float*)d_in[0];
    const float* normal  = (const float*)d_in[1];
    const float* r1      = (const float*)d_in[2];
    // d_in[3] = r2 -- unused by the reference computation
    const void*  mask    = d_in[4];
    const float* angs    = (const float*)d_in[5];

    const int B = in_sizes[2];            // 65536
    const int nBlocks = (B * S) / 256;    // 16384

    cosine_lobe_kernel<<<nBlocks, 256, 0, stream>>>(
        viewdir, normal, r1, mask, angs, (float*)d_out, B);
}